// Round 10
// baseline (1682.643 us; speedup 1.0000x reference)
//
#include <hip/hip_runtime.h>

// ---- problem constants ----
#define B_   2048
#define T_   512
#define H_   128
#define G_   512
#define R_   8      // batch rows per block
#define NTHR 512    // 8 symmetric waves; wave wv owns units [wv*16, wv*16+16)

typedef _Float16 f16;
typedef _Float16 f16x4 __attribute__((ext_vector_type(4)));
typedef _Float16 f16x8 __attribute__((ext_vector_type(8)));
typedef float    f32x4 __attribute__((ext_vector_type(4)));
typedef int      i32x2 __attribute__((ext_vector_type(2)));

// ---- LDS layout (bytes). h tiles: row stride 256 B, XOR swizzle ((row&7)<<4) ----
#define OFF_RING  0                       // h1 ring: 4 slots x [8][128] f16 = 8192
#define OFF_HB    8192                    // h2 state: 2 bufs x [8][128] f16 = 4096
#define OFF_XT    12288                   // x tiles: 2 bufs x 8 tok x 128 B = 2048
#define LDS_BYTES 14336

__device__ __forceinline__ float rcp_(float v) {
#if __has_builtin(__builtin_amdgcn_rcpf)
  return __builtin_amdgcn_rcpf(v);
#else
  return 1.0f / v;
#endif
}
__device__ __forceinline__ float sig_(float v)  { return rcp_(1.0f + __expf(-v)); }
__device__ __forceinline__ float tanh_(float v) { return 1.0f - 2.0f * rcp_(__expf(2.0f * v) + 1.0f); }

__device__ __forceinline__ f16x8 cvt8(const float* __restrict__ p) {
  float4 a = ((const float4*)p)[0];
  float4 b = ((const float4*)p)[1];
  f16x8 v;
  v[0]=(f16)a.x; v[1]=(f16)a.y; v[2]=(f16)a.z; v[3]=(f16)a.w;
  v[4]=(f16)b.x; v[5]=(f16)b.y; v[6]=(f16)b.z; v[7]=(f16)b.w;
  return v;
}
__device__ __forceinline__ f32x4 mfma16(f16x8 a, f16x8 b, f32x4 c) {
  return __builtin_amdgcn_mfma_f32_16x16x32_f16(a, b, c, 0, 0, 0);
}

// v_permlane32_swap: x = {a.lo, b.lo} (even-row spread), y = {a.hi, b.hi} (odd)
// HW-validated (rounds 5,6,9 passed with this path).
__device__ __forceinline__ void pls2_(float a, float b, float& x, float& y) {
#if __has_builtin(__builtin_amdgcn_permlane32_swap)
  i32x2 r = __builtin_amdgcn_permlane32_swap(__float_as_int(a), __float_as_int(b),
                                             false, false);
  x = __int_as_float(r.x); y = __int_as_float(r.y);
#else
  asm volatile("v_permlane32_swap_b32 %0, %1" : "+v"(a), "+v"(b));
  x = a; y = b;
#endif
}

// ---- setup kernel: w_ih1 f32[512][128] -> f16[512][128] in workspace ----
__global__ __launch_bounds__(256)
void cvt_w1(const float* __restrict__ src, f16* __restrict__ dst) {
  const int i = (int)blockIdx.x * 256 + (int)threadIdx.x;   // 16384 float4 groups
  const float4 v = ((const float4*)src)[i];
  f16x4 o; o[0]=(f16)v.x; o[1]=(f16)v.y; o[2]=(f16)v.z; o[3]=(f16)v.w;
  ((f16x4*)dst)[i] = o;
}

__global__ __launch_bounds__(NTHR, 2)
void lstm_v10(const float* __restrict__ x,
              const float* __restrict__ w_ih0, const float* __restrict__ w_hh0,
              const float* __restrict__ b_ih0, const float* __restrict__ b_hh0,
              const f16*   __restrict__ w1g,   const float* __restrict__ w_hh1,
              const float* __restrict__ b_ih1, const float* __restrict__ b_hh1,
              const float* __restrict__ fc_w,  const float* __restrict__ fc_b,
              float* __restrict__ out)
{
  extern __shared__ char lds[];
  char*  ringB = lds + OFF_RING;
  char*  hBB   = lds + OFF_HB;
  char*  xT    = lds + OFF_XT;

  const int tid  = (int)threadIdx.x;
  const int lane = tid & 63;
  const int wv   = tid >> 6;
  const int n    = lane & 15;
  const int hi   = lane >> 4;
  const int u0   = wv * 16;
  const int blk  = (int)blockIdx.x;
  const int rsw  = (n & 7) << 4;

  // zero ring + hB + xT (14336 B = 3584 dwords); xT pad must stay finite
  for (int i = tid; i < 3584; i += NTHR) ((unsigned*)lds)[i] = 0u;
  __syncthreads();

  // ---- wave 7: x prologue (chunk 0 -> xT buf0; chunk 1 -> regs) ----
  float xr0 = 0.f, xr1 = 0.f, xr2 = 0.f;
  if (wv == 7) {
    const int tok = lane >> 3, r = lane & 7;
    const size_t base = (size_t)(blk*R_ + r) * T_;
    const float a0 = x[(base + tok)*3+0];
    const float a1 = x[(base + tok)*3+1];
    const float a2 = x[(base + tok)*3+2];
    f16* w = (f16*)(xT + tok*128 + r*16);
    w[0] = (f16)a0; w[1] = (f16)a1; w[2] = (f16)a2;
    xr0 = x[(base + 8 + tok)*3+0];
    xr1 = x[(base + 8 + tok)*3+1];
    xr2 = x[(base + 8 + tok)*3+2];
  }

  // ---- resident weight fragments: 128 VGPRs (proven budget) ----
  f16x8 whh0f[4][4], whh1f[4][4];
  #pragma unroll
  for (int q = 0; q < 4; ++q)
    #pragma unroll
    for (int kc = 0; kc < 4; ++kc) {
      const int off = (q*H_ + u0 + n)*H_ + kc*32 + hi*8;
      whh0f[q][kc] = cvt8(w_hh0 + off);
      whh1f[q][kc] = cvt8(w_hh1 + off);
    }
  // padded w_ih0 B-frags (K=32; k>=3 zero; only hi==0 lanes carry data)
  f16x8 w0p[4];
  float b0[4], bP[4];
  #pragma unroll
  for (int q = 0; q < 4; ++q) {
    const int g = q*H_ + u0 + n;
    b0[q] = b_ih0[g] + b_hh0[g];
    bP[q] = b_ih1[g] + b_hh1[g];
    f16x8 z;
    #pragma unroll
    for (int e = 0; e < 8; ++e) z[e] = (f16)0.f;
    if (hi == 0) {
      z[0] = (f16)w_ih0[g*3+0];
      z[1] = (f16)w_ih0[g*3+1];
      z[2] = (f16)w_ih0[g*3+2];
    }
    w0p[q] = z;
  }

  int offA[4];
  #pragma unroll
  for (int kc = 0; kc < 4; ++kc)
    offA[kc] = (n&7)*256 + ((kc*64 + hi*16) ^ rsw);

  float cA0 = 0.f, cA1 = 0.f, cB0 = 0.f, cB1 = 0.f;
  f32x4 xpP[4];
  const int rowbase = (hi & 1)*4 + ((lane >= 32) ? 2 : 0);
  const int colb    = 2*(u0 + n);
  const int wOff0 = rowbase*256     + (colb ^ (rowbase<<4));
  const int wOff1 = (rowbase+1)*256 + (colb ^ ((rowbase+1)<<4));
  // loop-invariant base for this wave's w_ih1 slice (f16 elements)
  const f16* __restrict__ w1base = w1g + (size_t)(u0 + n)*H_ + hi*8;
  __syncthreads();

  // ---- phase lambdas (runtime s; templates avoided -> round-7 spill trap) ----
  auto xstage = [&](int s) {
    if (wv == 7 && (s & 7) == 3) {
      const int c = s >> 3;
      const int tok = lane >> 3, r = lane & 7;
      if (c <= 61) {
        const size_t base = (size_t)(blk*R_ + r) * T_ + (8*(c+2) + tok);
        const float a0 = x[base*3+0], a1 = x[base*3+1], a2 = x[base*3+2];
        f16* w = (f16*)(xT + ((c+1)&1)*1024 + tok*128 + r*16);
        w[0] = (f16)xr0; w[1] = (f16)xr1; w[2] = (f16)xr2;
        xr0 = a0; xr1 = a1; xr2 = a2;
      } else if (c == 62) {
        f16* w = (f16*)(xT + ((c+1)&1)*1024 + tok*128 + r*16);
        w[0] = (f16)xr0; w[1] = (f16)xr1; w[2] = (f16)xr2;
      }
    }
  };

  auto proj = [&](int s) {   // tokens (s-2 -> rows 0-7, s-1 -> rows 8-15), even s
    if ((s & 1) == 0 && s >= 2 && s <= T_) {
      const char* pa = ringB + ((n < 8) ? (((s-2)&3)*2048) : (((s-1)&3)*2048));
      #pragma unroll
      for (int q = 0; q < 4; ++q)
        { xpP[q][0]=bP[q]; xpP[q][1]=bP[q]; xpP[q][2]=bP[q]; xpP[q][3]=bP[q]; }
      // B-frags from global (L2-resident 128 KB), kc-pair batches (32 reg spike)
      #pragma unroll
      for (int kp = 0; kp < 2; ++kp) {
        f16x8 bf[2][4];
        #pragma unroll
        for (int kk = 0; kk < 2; ++kk) {
          const int kc = kp*2 + kk;
          #pragma unroll
          for (int q = 0; q < 4; ++q)
            bf[kk][q] = *(const f16x8*)(w1base + (size_t)q*H_*H_ + kc*32);
        }
        #pragma unroll
        for (int kk = 0; kk < 2; ++kk) {
          const int kc = kp*2 + kk;
          const f16x8 a = *(const f16x8*)(pa + offA[kc]);
          #pragma unroll
          for (int q = 0; q < 4; ++q)
            xpP[q] = mfma16(a, bf[kk][q], xpP[q]);
        }
      }
    }
  };

  auto l0 = [&](int s) {     // layer 0, token s
    if (s < T_) {
      const f16x8 ax = *(const f16x8*)(xT + ((s>>3)&1)*1024 + (s&7)*128 + (n&7)*16);
      f32x4 acc[4];
      #pragma unroll
      for (int q = 0; q < 4; ++q) {
        f32x4 a; a[0]=b0[q]; a[1]=b0[q]; a[2]=b0[q]; a[3]=b0[q];
        acc[q] = mfma16(ax, w0p[q], a);
      }
      const char* pa = ringB + (((s-1)&3)*2048);
      #pragma unroll
      for (int kc = 0; kc < 4; ++kc) {
        const f16x8 af = *(const f16x8*)(pa + offA[kc]);
        #pragma unroll
        for (int q = 0; q < 4; ++q) acc[q] = mfma16(af, whh0f[q][kc], acc[q]);
      }
      char* wr = ringB + ((s&3)*2048);
      float gA[4], gB[4], d0, d1;
      #pragma unroll
      for (int q = 0; q < 4; ++q) {
        pls2_(acc[q][0], acc[q][2], gA[q], d0);
        pls2_(acc[q][1], acc[q][3], gB[q], d1);
      }
      {
        const float iv = sig_(gA[0]), fv = sig_(gA[1]), gv = tanh_(gA[2]), ov = sig_(gA[3]);
        cA0 = fv*cA0 + iv*gv;
        *(f16*)(wr + wOff0) = (f16)(ov * tanh_(cA0));
      }
      {
        const float iv = sig_(gB[0]), fv = sig_(gB[1]), gv = tanh_(gB[2]), ov = sig_(gB[3]);
        cA1 = fv*cA1 + iv*gv;
        *(f16*)(wr + wOff1) = (f16)(ov * tanh_(cA1));
      }
    }
  };

  auto l1 = [&](int s) {     // layer 1, token s-2; odd tokens ride y-half of swap
    if (s >= 2) {
      const bool odd = (s & 1);
      const char* pb = hBB + (s&1)*2048;
      f32x4 acc[4];
      #pragma unroll
      for (int q = 0; q < 4; ++q) acc[q] = xpP[q];
      #pragma unroll
      for (int kc = 0; kc < 4; ++kc) {
        const f16x8 af = *(const f16x8*)(pb + offA[kc]);
        #pragma unroll
        for (int q = 0; q < 4; ++q) acc[q] = mfma16(af, whh1f[q][kc], acc[q]);
      }
      char* wr = hBB + (((s+1)&1)*2048);
      float gA[4], gB[4];
      #pragma unroll
      for (int q = 0; q < 4; ++q) {
        float ex, ey, fx, fy;
        pls2_(acc[q][0], acc[q][2], ex, ey);
        pls2_(acc[q][1], acc[q][3], fx, fy);
        gA[q] = odd ? ey : ex;
        gB[q] = odd ? fy : fx;
      }
      {
        const float iv = sig_(gA[0]), fv = sig_(gA[1]), gv = tanh_(gA[2]), ov = sig_(gA[3]);
        cB0 = fv*cB0 + iv*gv;
        *(f16*)(wr + wOff0) = (f16)(ov * tanh_(cB0));
      }
      {
        const float iv = sig_(gB[0]), fv = sig_(gB[1]), gv = tanh_(gB[2]), ov = sig_(gB[3]);
        cB1 = fv*cB1 + iv*gv;
        *(f16*)(wr + wOff1) = (f16)(ov * tanh_(cB1));
      }
    }
  };

  // ---- main loop: wave-parity phase stagger (round-9 win, kept) ----
  for (int s = 0; s < T_ + 2; ++s) {
    if (wv & 1) {            // odd waves (incl. wave 7 w/ x staging): L0 first
      xstage(s);
      l0(s);
      proj(s);
      l1(s);
    } else {                 // even waves: proj/L1 first, L0 last
      proj(s);
      l1(s);
      l0(s);
    }
    __syncthreads();
  }

  // ---- FC head: final h2 in hBB buf (T_+2)&1 == 0 ----
  if (tid < R_*2) {
    const int r = tid >> 1, o = tid & 1;
    float acc = fc_b[o];
    #pragma unroll 4
    for (int d = 0; d < H_; ++d) {
      const f16 hv = *(const f16*)(hBB + r*256 + ((2*d) ^ ((r&7)<<4)));
      acc += (float)hv * fc_w[o*H_ + d];
    }
    out[(blk*R_ + r)*2 + o] = acc;
  }
}

extern "C" void kernel_launch(void* const* d_in, const int* in_sizes, int n_in,
                              void* d_out, int out_size, void* d_ws, size_t ws_size,
                              hipStream_t stream) {
  const float* x     = (const float*)d_in[0];
  const float* w_ih0 = (const float*)d_in[1];
  const float* w_hh0 = (const float*)d_in[2];
  const float* b_ih0 = (const float*)d_in[3];
  const float* b_hh0 = (const float*)d_in[4];
  const float* w_ih1 = (const float*)d_in[5];
  const float* w_hh1 = (const float*)d_in[6];
  const float* b_ih1 = (const float*)d_in[7];
  const float* b_hh1 = (const float*)d_in[8];
  const float* fc_w  = (const float*)d_in[9];
  const float* fc_b  = (const float*)d_in[10];
  (void)in_sizes; (void)n_in; (void)out_size; (void)ws_size;

  f16* w1g = (f16*)d_ws;                         // 512*128*2 = 128 KB

  // stage 1: pre-convert w_ih1 to f16 (stream-ordered before main kernel)
  cvt_w1<<<G_*H_/4/256, 256, 0, stream>>>(w_ih1, w1g);

  // stage 2: fused LSTM
  lstm_v10<<<B_/R_, NTHR, LDS_BYTES, stream>>>(
      x, w_ih0, w_hh0, b_ih0, b_hh0, w1g, w_hh1, b_ih1, b_hh1,
      fc_w, fc_b, (float*)d_out);
}

// Round 11
// 857.237 us; speedup vs baseline: 1.9629x; 1.9629x over previous
//
#include <hip/hip_runtime.h>

// ---- problem constants ----
#define B_   2048
#define T_   512
#define H_   128
#define G_   512
#define R_   8      // batch rows per block
#define NTHR 512    // 8 symmetric waves; wave wv owns units [wv*16, wv*16+16)

typedef _Float16 f16;
typedef _Float16 f16x8 __attribute__((ext_vector_type(8)));
typedef float    f32x4 __attribute__((ext_vector_type(4)));
typedef int      i32x2 __attribute__((ext_vector_type(2)));

// ---- LDS layout (bytes) ----
// w1L: per-wave lane-linear frag banks: addr = wv*16384 + (q*4+kc)*1024 + lane*16
//      (contiguous 1024-B per wave-read -> minimum 8 phases, ZERO bank conflicts)
// h tiles: row stride 256 B, XOR swizzle ((row&7)<<4) (8 rows -> conflict-free)
#define OFF_W1    0                       // w_ih1 frag banks = 131072
#define OFF_RING  131072                  // h1 ring: 4 slots x [8][128] f16 = 8192
#define OFF_HB    139264                  // h2 state: 2 bufs x [8][128] f16 = 4096
#define OFF_XT    143360                  // x tiles: 2 bufs x 8 tok x 128 B = 2048
#define LDS_BYTES 145408

__device__ __forceinline__ float rcp_(float v) {
#if __has_builtin(__builtin_amdgcn_rcpf)
  return __builtin_amdgcn_rcpf(v);
#else
  return 1.0f / v;
#endif
}
__device__ __forceinline__ float sig_(float v)  { return rcp_(1.0f + __expf(-v)); }
__device__ __forceinline__ float tanh_(float v) { return 1.0f - 2.0f * rcp_(__expf(2.0f * v) + 1.0f); }

__device__ __forceinline__ f16x8 cvt8(const float* __restrict__ p) {
  float4 a = ((const float4*)p)[0];
  float4 b = ((const float4*)p)[1];
  f16x8 v;
  v[0]=(f16)a.x; v[1]=(f16)a.y; v[2]=(f16)a.z; v[3]=(f16)a.w;
  v[4]=(f16)b.x; v[5]=(f16)b.y; v[6]=(f16)b.z; v[7]=(f16)b.w;
  return v;
}
__device__ __forceinline__ f32x4 mfma16(f16x8 a, f16x8 b, f32x4 c) {
  return __builtin_amdgcn_mfma_f32_16x16x32_f16(a, b, c, 0, 0, 0);
}

// v_permlane32_swap: x = {a.lo, b.lo} (even-row spread), y = {a.hi, b.hi} (odd)
// HW-validated (rounds 5,6,9 passed with this path).
__device__ __forceinline__ void pls2_(float a, float b, float& x, float& y) {
#if __has_builtin(__builtin_amdgcn_permlane32_swap)
  i32x2 r = __builtin_amdgcn_permlane32_swap(__float_as_int(a), __float_as_int(b),
                                             false, false);
  x = __int_as_float(r.x); y = __int_as_float(r.y);
#else
  asm volatile("v_permlane32_swap_b32 %0, %1" : "+v"(a), "+v"(b));
  x = a; y = b;
#endif
}

__global__ __launch_bounds__(NTHR, 2)
void lstm_v11(const float* __restrict__ x,
              const float* __restrict__ w_ih0, const float* __restrict__ w_hh0,
              const float* __restrict__ b_ih0, const float* __restrict__ b_hh0,
              const float* __restrict__ w_ih1, const float* __restrict__ w_hh1,
              const float* __restrict__ b_ih1, const float* __restrict__ b_hh1,
              const float* __restrict__ fc_w,  const float* __restrict__ fc_b,
              float* __restrict__ out)
{
  extern __shared__ char lds[];
  char*  w1L   = lds + OFF_W1;
  char*  ringB = lds + OFF_RING;
  char*  hBB   = lds + OFF_HB;
  char*  xT    = lds + OFF_XT;

  const int tid  = (int)threadIdx.x;
  const int lane = tid & 63;
  const int wv   = tid >> 6;
  const int n    = lane & 15;
  const int hi   = lane >> 4;
  const int u0   = wv * 16;
  const int blk  = (int)blockIdx.x;
  const int rsw  = (n & 7) << 4;

  // ---- stage w_ih1 -> per-wave lane-linear frag banks ----
  // frag(wv,q,kc,lane) holds w_ih1[g = q*128 + wv*16 + (lane&15)]
  //                          [k = (kc*4 + lane>>4)*8 .. +8) as f16x8
  for (int idx = tid; idx < 8192; idx += NTHR) {
    const int g  = idx >> 4, c  = idx & 15;       // c = k-chunk of 8
    const int w  = (g >> 4) & 7, nn = g & 15, q = g >> 7;
    const int kc = c >> 2,  hh = c & 3;
    f16x8 v = cvt8(w_ih1 + g*H_ + c*8);
    *(f16x8*)(w1L + w*16384 + (q*4+kc)*1024 + ((hh<<4) + nn)*16) = v;
  }
  // zero ring + hB + xT (14336 B = 3584 dwords); xT pad must stay finite
  for (int i = tid; i < 3584; i += NTHR) ((unsigned*)ringB)[i] = 0u;
  __syncthreads();

  // ---- wave 7: x prologue (chunk 0 -> xT buf0; chunk 1 -> regs) ----
  float xr0 = 0.f, xr1 = 0.f, xr2 = 0.f;
  if (wv == 7) {
    const int tok = lane >> 3, r = lane & 7;
    const size_t base = (size_t)(blk*R_ + r) * T_;
    const float a0 = x[(base + tok)*3+0];
    const float a1 = x[(base + tok)*3+1];
    const float a2 = x[(base + tok)*3+2];
    f16* w = (f16*)(xT + tok*128 + r*16);
    w[0] = (f16)a0; w[1] = (f16)a1; w[2] = (f16)a2;
    xr0 = x[(base + 8 + tok)*3+0];
    xr1 = x[(base + 8 + tok)*3+1];
    xr2 = x[(base + 8 + tok)*3+2];
  }

  // ---- resident weight fragments: 128 VGPRs (proven budget; do NOT grow) ----
  f16x8 whh0f[4][4], whh1f[4][4];
  #pragma unroll
  for (int q = 0; q < 4; ++q)
    #pragma unroll
    for (int kc = 0; kc < 4; ++kc) {
      const int off = (q*H_ + u0 + n)*H_ + kc*32 + hi*8;
      whh0f[q][kc] = cvt8(w_hh0 + off);
      whh1f[q][kc] = cvt8(w_hh1 + off);
    }
  // padded w_ih0 B-frags (K=32; k>=3 zero; only hi==0 lanes carry data)
  f16x8 w0p[4];
  float b0[4], bP[4];
  #pragma unroll
  for (int q = 0; q < 4; ++q) {
    const int g = q*H_ + u0 + n;
    b0[q] = b_ih0[g] + b_hh0[g];
    bP[q] = b_ih1[g] + b_hh1[g];
    f16x8 z;
    #pragma unroll
    for (int e = 0; e < 8; ++e) z[e] = (f16)0.f;
    if (hi == 0) {
      z[0] = (f16)w_ih0[g*3+0];
      z[1] = (f16)w_ih0[g*3+1];
      z[2] = (f16)w_ih0[g*3+2];
    }
    w0p[q] = z;
  }

  int offA[4];
  #pragma unroll
  for (int kc = 0; kc < 4; ++kc)
    offA[kc] = (n&7)*256 + ((kc*64 + hi*16) ^ rsw);

  float cA0 = 0.f, cA1 = 0.f, cB0 = 0.f, cB1 = 0.f;
  f32x4 xpP[4];
  const int rowbase = (hi & 1)*4 + ((lane >= 32) ? 2 : 0);
  const int colb    = 2*(u0 + n);
  const int wOff0 = rowbase*256     + (colb ^ (rowbase<<4));
  const int wOff1 = (rowbase+1)*256 + (colb ^ ((rowbase+1)<<4));
  // single base pointer for this lane's w1 frags; reads use imm offsets only
  const char* __restrict__ w1lane = w1L + wv*16384 + lane*16;
  __syncthreads();

  // ---- phase lambdas (runtime s; templates avoided -> round-7 spill trap) ----
  auto xstage = [&](int s) {
    if (wv == 7 && (s & 7) == 3) {
      const int c = s >> 3;
      const int tok = lane >> 3, r = lane & 7;
      if (c <= 61) {
        const size_t base = (size_t)(blk*R_ + r) * T_ + (8*(c+2) + tok);
        const float a0 = x[base*3+0], a1 = x[base*3+1], a2 = x[base*3+2];
        f16* w = (f16*)(xT + ((c+1)&1)*1024 + tok*128 + r*16);
        w[0] = (f16)xr0; w[1] = (f16)xr1; w[2] = (f16)xr2;
        xr0 = a0; xr1 = a1; xr2 = a2;
      } else if (c == 62) {
        f16* w = (f16*)(xT + ((c+1)&1)*1024 + tok*128 + r*16);
        w[0] = (f16)xr0; w[1] = (f16)xr1; w[2] = (f16)xr2;
      }
    }
  };

  auto proj = [&](int s) {   // tokens (s-2 -> rows 0-7, s-1 -> rows 8-15), even s
    if ((s & 1) == 0 && s >= 2 && s <= T_) {
      const char* pa = ringB + ((n < 8) ? (((s-2)&3)*2048) : (((s-1)&3)*2048));
      #pragma unroll
      for (int q = 0; q < 4; ++q)
        { xpP[q][0]=bP[q]; xpP[q][1]=bP[q]; xpP[q][2]=bP[q]; xpP[q][3]=bP[q]; }
      #pragma unroll
      for (int kc = 0; kc < 4; ++kc) {
        const f16x8 a = *(const f16x8*)(pa + offA[kc]);
        #pragma unroll
        for (int q = 0; q < 4; ++q) {
          const f16x8 bf = *(const f16x8*)(w1lane + (q*4 + kc)*1024);
          xpP[q] = mfma16(a, bf, xpP[q]);
        }
      }
    }
  };

  auto l0 = [&](int s) {     // layer 0, token s
    if (s < T_) {
      const f16x8 ax = *(const f16x8*)(xT + ((s>>3)&1)*1024 + (s&7)*128 + (n&7)*16);
      f32x4 acc[4];
      #pragma unroll
      for (int q = 0; q < 4; ++q) {
        f32x4 a; a[0]=b0[q]; a[1]=b0[q]; a[2]=b0[q]; a[3]=b0[q];
        acc[q] = mfma16(ax, w0p[q], a);
      }
      const char* pa = ringB + (((s-1)&3)*2048);
      #pragma unroll
      for (int kc = 0; kc < 4; ++kc) {
        const f16x8 af = *(const f16x8*)(pa + offA[kc]);
        #pragma unroll
        for (int q = 0; q < 4; ++q) acc[q] = mfma16(af, whh0f[q][kc], acc[q]);
      }
      char* wr = ringB + ((s&3)*2048);
      float gA[4], gB[4], d0, d1;
      #pragma unroll
      for (int q = 0; q < 4; ++q) {
        pls2_(acc[q][0], acc[q][2], gA[q], d0);
        pls2_(acc[q][1], acc[q][3], gB[q], d1);
      }
      {
        const float iv = sig_(gA[0]), fv = sig_(gA[1]), gv = tanh_(gA[2]), ov = sig_(gA[3]);
        cA0 = fv*cA0 + iv*gv;
        *(f16*)(wr + wOff0) = (f16)(ov * tanh_(cA0));
      }
      {
        const float iv = sig_(gB[0]), fv = sig_(gB[1]), gv = tanh_(gB[2]), ov = sig_(gB[3]);
        cA1 = fv*cA1 + iv*gv;
        *(f16*)(wr + wOff1) = (f16)(ov * tanh_(cA1));
      }
    }
  };

  auto l1 = [&](int s) {     // layer 1, token s-2; odd tokens ride y-half of swap
    if (s >= 2) {
      const bool odd = (s & 1);
      const char* pb = hBB + (s&1)*2048;
      f32x4 acc[4];
      #pragma unroll
      for (int q = 0; q < 4; ++q) acc[q] = xpP[q];
      #pragma unroll
      for (int kc = 0; kc < 4; ++kc) {
        const f16x8 af = *(const f16x8*)(pb + offA[kc]);
        #pragma unroll
        for (int q = 0; q < 4; ++q) acc[q] = mfma16(af, whh1f[q][kc], acc[q]);
      }
      char* wr = hBB + (((s+1)&1)*2048);
      float gA[4], gB[4];
      #pragma unroll
      for (int q = 0; q < 4; ++q) {
        float ex, ey, fx, fy;
        pls2_(acc[q][0], acc[q][2], ex, ey);
        pls2_(acc[q][1], acc[q][3], fx, fy);
        gA[q] = odd ? ey : ex;
        gB[q] = odd ? fy : fx;
      }
      {
        const float iv = sig_(gA[0]), fv = sig_(gA[1]), gv = tanh_(gA[2]), ov = sig_(gA[3]);
        cB0 = fv*cB0 + iv*gv;
        *(f16*)(wr + wOff0) = (f16)(ov * tanh_(cB0));
      }
      {
        const float iv = sig_(gB[0]), fv = sig_(gB[1]), gv = tanh_(gB[2]), ov = sig_(gB[3]);
        cB1 = fv*cB1 + iv*gv;
        *(f16*)(wr + wOff1) = (f16)(ov * tanh_(cB1));
      }
    }
  };

  // ---- main loop: wave-parity phase stagger (round-9 win, kept) ----
  for (int s = 0; s < T_ + 2; ++s) {
    if (wv & 1) {            // odd waves (incl. wave 7 w/ x staging): L0 first
      xstage(s);
      l0(s);
      proj(s);
      l1(s);
    } else {                 // even waves: proj/L1 first, L0 last
      proj(s);
      l1(s);
      l0(s);
    }
    __syncthreads();
  }

  // ---- FC head: final h2 in hBB buf (T_+2)&1 == 0 ----
  if (tid < R_*2) {
    const int r = tid >> 1, o = tid & 1;
    float acc = fc_b[o];
    #pragma unroll 4
    for (int d = 0; d < H_; ++d) {
      const f16 hv = *(const f16*)(hBB + r*256 + ((2*d) ^ ((r&7)<<4)));
      acc += (float)hv * fc_w[o*H_ + d];
    }
    out[(blk*R_ + r)*2 + o] = acc;
  }
}

extern "C" void kernel_launch(void* const* d_in, const int* in_sizes, int n_in,
                              void* d_out, int out_size, void* d_ws, size_t ws_size,
                              hipStream_t stream) {
  const float* x     = (const float*)d_in[0];
  const float* w_ih0 = (const float*)d_in[1];
  const float* w_hh0 = (const float*)d_in[2];
  const float* b_ih0 = (const float*)d_in[3];
  const float* b_hh0 = (const float*)d_in[4];
  const float* w_ih1 = (const float*)d_in[5];
  const float* w_hh1 = (const float*)d_in[6];
  const float* b_ih1 = (const float*)d_in[7];
  const float* b_hh1 = (const float*)d_in[8];
  const float* fc_w  = (const float*)d_in[9];
  const float* fc_b  = (const float*)d_in[10];
  (void)in_sizes; (void)n_in; (void)out_size; (void)d_ws; (void)ws_size;

  hipFuncSetAttribute((const void*)lstm_v11,
                      hipFuncAttributeMaxDynamicSharedMemorySize, LDS_BYTES);

  lstm_v11<<<B_/R_, NTHR, LDS_BYTES, stream>>>(
      x, w_ih0, w_hh0, b_ih0, b_hh0, w_ih1, w_hh1, b_ih1, b_hh1,
      fc_w, fc_b, (float*)d_out);
}

// Round 12
// 716.325 us; speedup vs baseline: 2.3490x; 1.1967x over previous
//
#include <hip/hip_runtime.h>

// ---- problem constants ----
#define B_   2048
#define T_   512
#define H_   128
#define G_   512
#define R_   8      // batch rows per block
#define NTHR 1024   // 16 waves: 0-7 = layer0, 8-15 = layer1 + proj

typedef _Float16 f16;
typedef _Float16 f16x4 __attribute__((ext_vector_type(4)));
typedef _Float16 f16x8 __attribute__((ext_vector_type(8)));
typedef float    f32x4 __attribute__((ext_vector_type(4)));
typedef int      i32x2 __attribute__((ext_vector_type(2)));

// ---- LDS layout (bytes) ----
// w1L: per-wave lane-linear frag banks (v11, conflict-free):
//      addr = w*16384 + (q*4+kc)*1024 + lane*16
// h tiles: row stride 256 B, XOR swizzle ((row&7)<<4)
// xT: K=16 A-tiles: 2 bufs x 8 tok x 256 B (row r: halves 0-3 = {x0,x1,x2,1}, rest 0)
#define OFF_W1    0                       // 131072
#define OFF_RING  131072                  // h1 ring: 4 slots x 2048 = 8192
#define OFF_HB    139264                  // h2 state: 2 bufs x 2048 = 4096
#define OFF_XT    143360                  // 4096
#define LDS_BYTES 147456

__device__ __forceinline__ float rcp_(float v) {
#if __has_builtin(__builtin_amdgcn_rcpf)
  return __builtin_amdgcn_rcpf(v);
#else
  return 1.0f / v;
#endif
}
__device__ __forceinline__ float sig_(float v)  { return rcp_(1.0f + __expf(-v)); }
__device__ __forceinline__ float tanh_(float v) { return 1.0f - 2.0f * rcp_(__expf(2.0f * v) + 1.0f); }

__device__ __forceinline__ f16x8 cvt8(const float* __restrict__ p) {
  float4 a = ((const float4*)p)[0];
  float4 b = ((const float4*)p)[1];
  f16x8 v;
  v[0]=(f16)a.x; v[1]=(f16)a.y; v[2]=(f16)a.z; v[3]=(f16)a.w;
  v[4]=(f16)b.x; v[5]=(f16)b.y; v[6]=(f16)b.z; v[7]=(f16)b.w;
  return v;
}
__device__ __forceinline__ f32x4 mfma16(f16x8 a, f16x8 b, f32x4 c) {
  return __builtin_amdgcn_mfma_f32_16x16x32_f16(a, b, c, 0, 0, 0);
}
__device__ __forceinline__ f32x4 mfma16k16(f16x4 a, f16x4 b, f32x4 c) {
  return __builtin_amdgcn_mfma_f32_16x16x16f16(a, b, c, 0, 0, 0);
}

// v_permlane32_swap: x = {a.lo, b.lo} (even-row spread), y = {a.hi, b.hi} (odd)
__device__ __forceinline__ void pls2_(float a, float b, float& x, float& y) {
#if __has_builtin(__builtin_amdgcn_permlane32_swap)
  i32x2 r = __builtin_amdgcn_permlane32_swap(__float_as_int(a), __float_as_int(b),
                                             false, false);
  x = __int_as_float(r.x); y = __int_as_float(r.y);
#else
  asm volatile("v_permlane32_swap_b32 %0, %1" : "+v"(a), "+v"(b));
  x = a; y = b;
#endif
}

__global__ __launch_bounds__(NTHR)
void lstm_v12(const float* __restrict__ x,
              const float* __restrict__ w_ih0, const float* __restrict__ w_hh0,
              const float* __restrict__ b_ih0, const float* __restrict__ b_hh0,
              const float* __restrict__ w_ih1, const float* __restrict__ w_hh1,
              const float* __restrict__ b_ih1, const float* __restrict__ b_hh1,
              const float* __restrict__ fc_w,  const float* __restrict__ fc_b,
              float* __restrict__ out)
{
  extern __shared__ char lds[];
  char*  w1L   = lds + OFF_W1;
  char*  ringB = lds + OFF_RING;
  char*  hBB   = lds + OFF_HB;
  char*  xT    = lds + OFF_XT;

  const int tid  = (int)threadIdx.x;
  const int lane = tid & 63;
  const int wv   = tid >> 6;          // 0..15
  const int n    = lane & 15;
  const int hi   = lane >> 4;
  const int u0   = (wv & 7) * 16;
  const int blk  = (int)blockIdx.x;
  const int rsw  = (n & 7) << 4;

  // ---- stage w_ih1 -> per-wave lane-linear frag banks (conflict-free reads) ----
  for (int idx = tid; idx < 8192; idx += NTHR) {
    const int g  = idx >> 4, c  = idx & 15;
    const int w  = (g >> 4) & 7, nn = g & 15, q = g >> 7;
    const int kc = c >> 2,  hh = c & 3;
    f16x8 v = cvt8(w_ih1 + g*H_ + c*8);
    *(f16x8*)(w1L + w*16384 + (q*4+kc)*1024 + ((hh<<4) + nn)*16) = v;
  }
  // zero ring + hB + xT (16384 B = 4096 dwords); xT zero-fill is load-bearing
  for (int i = tid; i < 4096; i += NTHR) ((unsigned*)ringB)[i] = 0u;

  // per-lane shared constants
  int offA[4];
  #pragma unroll
  for (int kc = 0; kc < 4; ++kc)
    offA[kc] = (n&7)*256 + ((kc*64 + hi*16) ^ rsw);
  const int rowbase = (hi & 1)*4 + ((lane >= 32) ? 2 : 0);
  const int colb    = 2*(u0 + n);
  const int wOff0 = rowbase*256     + (colb ^ (rowbase<<4));
  const int wOff1 = (rowbase+1)*256 + (colb ^ ((rowbase+1)<<4));
  __syncthreads();

  if (wv < 8) {
    // ================= ROLE 0: layer-0 recurrence (waves 0-7) =================
    // wave 7: x prologue (chunk 0 -> xT buf0; chunk 1 -> regs)
    float xr0 = 0.f, xr1 = 0.f, xr2 = 0.f;
    if (wv == 7) {
      const int tok = lane >> 3, r = lane & 7;
      const size_t base = (size_t)(blk*R_ + r) * T_;
      f16x4 v; v[0] = (f16)x[(base + tok)*3+0];
               v[1] = (f16)x[(base + tok)*3+1];
               v[2] = (f16)x[(base + tok)*3+2];
               v[3] = (f16)1.f;
      *(f16x4*)(xT + tok*256 + r*32) = v;
      xr0 = x[(base + 8 + tok)*3+0];
      xr1 = x[(base + 8 + tok)*3+1];
      xr2 = x[(base + 8 + tok)*3+2];
    }
    // resident whh0 fragments (64 regs, branch-local)
    f16x8 whh0f[4][4];
    #pragma unroll
    for (int q = 0; q < 4; ++q)
      #pragma unroll
      for (int kc = 0; kc < 4; ++kc)
        whh0f[q][kc] = cvt8(w_hh0 + (q*H_ + u0 + n)*H_ + kc*32 + hi*8);
    // K=16 x-projection B-frags: k=0..2 = w_ih0 row, k=3 = fused bias (hi==0 only)
    f16x4 w0px[4];
    #pragma unroll
    for (int q = 0; q < 4; ++q) {
      const int g = q*H_ + u0 + n;
      f16x4 z; z[0]=(f16)0.f; z[1]=(f16)0.f; z[2]=(f16)0.f; z[3]=(f16)0.f;
      if (hi == 0) {
        z[0] = (f16)w_ih0[g*3+0];
        z[1] = (f16)w_ih0[g*3+1];
        z[2] = (f16)w_ih0[g*3+2];
        z[3] = (f16)(b_ih0[g] + b_hh0[g]);
      }
      w0px[q] = z;
    }
    float cA0 = 0.f, cA1 = 0.f;
    __syncthreads();

    for (int s = 0; s < T_ + 2; ++s) {
      // x staging: wave 7, once per 8 steps
      if (wv == 7 && (s & 7) == 3) {
        const int c = s >> 3;
        const int tok = lane >> 3, r = lane & 7;
        if (c <= 61) {
          const size_t base = (size_t)(blk*R_ + r) * T_ + (8*(c+2) + tok);
          const float a0 = x[base*3+0], a1 = x[base*3+1], a2 = x[base*3+2];
          f16x4 v; v[0]=(f16)xr0; v[1]=(f16)xr1; v[2]=(f16)xr2; v[3]=(f16)1.f;
          *(f16x4*)(xT + ((c+1)&1)*2048 + tok*256 + r*32) = v;
          xr0 = a0; xr1 = a1; xr2 = a2;
        } else if (c == 62) {
          f16x4 v; v[0]=(f16)xr0; v[1]=(f16)xr1; v[2]=(f16)xr2; v[3]=(f16)1.f;
          *(f16x4*)(xT + ((c+1)&1)*2048 + tok*256 + r*32) = v;
        }
      }
      if (s < T_) {
        const f16x4 ax = *(const f16x4*)(xT + ((s>>3)&1)*2048 + (s&7)*256
                                         + (n&7)*32 + hi*8);
        f32x4 z4; z4[0]=0.f; z4[1]=0.f; z4[2]=0.f; z4[3]=0.f;
        f32x4 acc[4];
        #pragma unroll
        for (int q = 0; q < 4; ++q) acc[q] = mfma16k16(ax, w0px[q], z4);
        const char* pa = ringB + (((s-1)&3)*2048);
        #pragma unroll
        for (int kc = 0; kc < 4; ++kc) {
          const f16x8 af = *(const f16x8*)(pa + offA[kc]);
          #pragma unroll
          for (int q = 0; q < 4; ++q) acc[q] = mfma16(af, whh0f[q][kc], acc[q]);
        }
        char* wr = ringB + ((s&3)*2048);
        float gA[4], gB[4], d0, d1;
        #pragma unroll
        for (int q = 0; q < 4; ++q) {
          pls2_(acc[q][0], acc[q][2], gA[q], d0);
          pls2_(acc[q][1], acc[q][3], gB[q], d1);
        }
        {
          const float iv = sig_(gA[0]), fv = sig_(gA[1]), gv = tanh_(gA[2]), ov = sig_(gA[3]);
          cA0 = fv*cA0 + iv*gv;
          *(f16*)(wr + wOff0) = (f16)(ov * tanh_(cA0));
        }
        {
          const float iv = sig_(gB[0]), fv = sig_(gB[1]), gv = tanh_(gB[2]), ov = sig_(gB[3]);
          cA1 = fv*cA1 + iv*gv;
          *(f16*)(wr + wOff1) = (f16)(ov * tanh_(cA1));
        }
      }
      __syncthreads();
    }
  } else {
    // ============ ROLE 1: layer-1 recurrence + input proj (waves 8-15) ============
    f16x8 whh1f[4][4];
    #pragma unroll
    for (int q = 0; q < 4; ++q)
      #pragma unroll
      for (int kc = 0; kc < 4; ++kc)
        whh1f[q][kc] = cvt8(w_hh1 + (q*H_ + u0 + n)*H_ + kc*32 + hi*8);
    float bP[4];
    #pragma unroll
    for (int q = 0; q < 4; ++q) {
      const int g = q*H_ + u0 + n;
      bP[q] = b_ih1[g] + b_hh1[g];
    }
    float cB0 = 0.f, cB1 = 0.f;
    f32x4 xpP[4];
    const char* __restrict__ w1lane = w1L + (wv & 7)*16384 + lane*16;
    __syncthreads();

    for (int s = 0; s < T_ + 2; ++s) {
      // proj: tokens (s-2 -> rows 0-7, s-1 -> rows 8-15), even steps
      if ((s & 1) == 0 && s >= 2 && s <= T_) {
        const char* pa = ringB + ((n < 8) ? (((s-2)&3)*2048) : (((s-1)&3)*2048));
        #pragma unroll
        for (int q = 0; q < 4; ++q)
          { xpP[q][0]=bP[q]; xpP[q][1]=bP[q]; xpP[q][2]=bP[q]; xpP[q][3]=bP[q]; }
        #pragma unroll
        for (int kc = 0; kc < 4; ++kc) {
          const f16x8 a = *(const f16x8*)(pa + offA[kc]);
          #pragma unroll
          for (int q = 0; q < 4; ++q) {
            const f16x8 bf = *(const f16x8*)(w1lane + (q*4 + kc)*1024);
            xpP[q] = mfma16(a, bf, xpP[q]);
          }
        }
      }
      // layer 1 (token s-2); odd tokens ride y-half of swap
      if (s >= 2) {
        const bool odd = (s & 1);
        const char* pb = hBB + (s&1)*2048;
        f32x4 acc[4];
        {
          const f16x8 af = *(const f16x8*)(pb + offA[0]);
          #pragma unroll
          for (int q = 0; q < 4; ++q) acc[q] = mfma16(af, whh1f[q][0], xpP[q]);
        }
        #pragma unroll
        for (int kc = 1; kc < 4; ++kc) {
          const f16x8 af = *(const f16x8*)(pb + offA[kc]);
          #pragma unroll
          for (int q = 0; q < 4; ++q) acc[q] = mfma16(af, whh1f[q][kc], acc[q]);
        }
        char* wr = hBB + (((s+1)&1)*2048);
        float gA[4], gB[4];
        #pragma unroll
        for (int q = 0; q < 4; ++q) {
          float ex, ey, fx, fy;
          pls2_(acc[q][0], acc[q][2], ex, ey);
          pls2_(acc[q][1], acc[q][3], fx, fy);
          gA[q] = odd ? ey : ex;
          gB[q] = odd ? fy : fx;
        }
        {
          const float iv = sig_(gA[0]), fv = sig_(gA[1]), gv = tanh_(gA[2]), ov = sig_(gA[3]);
          cB0 = fv*cB0 + iv*gv;
          *(f16*)(wr + wOff0) = (f16)(ov * tanh_(cB0));
        }
        {
          const float iv = sig_(gB[0]), fv = sig_(gB[1]), gv = tanh_(gB[2]), ov = sig_(gB[3]);
          cB1 = fv*cB1 + iv*gv;
          *(f16*)(wr + wOff1) = (f16)(ov * tanh_(cB1));
        }
      }
      __syncthreads();
    }
  }

  // ---- FC head: final h2 in hBB buf (T_+2)&1 == 0 ----
  if (tid < R_*2) {
    const int r = tid >> 1, o = tid & 1;
    float acc = fc_b[o];
    #pragma unroll 4
    for (int d = 0; d < H_; ++d) {
      const f16 hv = *(const f16*)(hBB + r*256 + ((2*d) ^ ((r&7)<<4)));
      acc += (float)hv * fc_w[o*H_ + d];
    }
    out[(blk*R_ + r)*2 + o] = acc;
  }
}

extern "C" void kernel_launch(void* const* d_in, const int* in_sizes, int n_in,
                              void* d_out, int out_size, void* d_ws, size_t ws_size,
                              hipStream_t stream) {
  const float* x     = (const float*)d_in[0];
  const float* w_ih0 = (const float*)d_in[1];
  const float* w_hh0 = (const float*)d_in[2];
  const float* b_ih0 = (const float*)d_in[3];
  const float* b_hh0 = (const float*)d_in[4];
  const float* w_ih1 = (const float*)d_in[5];
  const float* w_hh1 = (const float*)d_in[6];
  const float* b_ih1 = (const float*)d_in[7];
  const float* b_hh1 = (const float*)d_in[8];
  const float* fc_w  = (const float*)d_in[9];
  const float* fc_b  = (const float*)d_in[10];
  (void)in_sizes; (void)n_in; (void)out_size; (void)d_ws; (void)ws_size;

  hipFuncSetAttribute((const void*)lstm_v12,
                      hipFuncAttributeMaxDynamicSharedMemorySize, LDS_BYTES);

  lstm_v12<<<B_/R_, NTHR, LDS_BYTES, stream>>>(
      x, w_ih0, w_hh0, b_ih0, b_hh0, w_ih1, w_hh1, b_ih1, b_hh1,
      fc_w, fc_b, (float*)d_out);
}

// Round 13
// 708.123 us; speedup vs baseline: 2.3762x; 1.0116x over previous
//
#include <hip/hip_runtime.h>

// ---- problem constants ----
#define B_   2048
#define T_   512
#define H_   128
#define G_   512
#define R_   8      // batch rows per block
#define NTHR 1024   // 16 waves: 0-7 = layer0, 8-15 = layer1 + proj

typedef _Float16 f16;
typedef _Float16 f16x4 __attribute__((ext_vector_type(4)));
typedef _Float16 f16x8 __attribute__((ext_vector_type(8)));
typedef float    f32x4 __attribute__((ext_vector_type(4)));
typedef int      i32x2 __attribute__((ext_vector_type(2)));

#define L2E   1.44269504f
#define L2E2  2.88539008f

// ---- LDS layout (bytes) ----
// w1L: per-wave lane-linear frag banks: addr = w*16384 + (q*4+kc)*1024 + lane*16
// h tiles: row stride 256 B, XOR swizzle ((row&7)<<4)
// xT: K=16 A-tiles: 2 bufs x 8 tok x 256 B (row r halves 0-3 = {x0,x1,x2,1})
#define OFF_W1    0                       // 131072
#define OFF_RING  131072                  // h1 ring: 4 slots x 2048 = 8192
#define OFF_HB    139264                  // h2 state: 2 bufs x 2048 = 4096
#define OFF_XT    143360                  // 4096
#define LDS_BYTES 147456

__device__ __forceinline__ float rcp_(float v) {
#if __has_builtin(__builtin_amdgcn_rcpf)
  return __builtin_amdgcn_rcpf(v);
#else
  return 1.0f / v;
#endif
}
__device__ __forceinline__ float exp2i_(float v) {
#if __has_builtin(__builtin_amdgcn_exp2f)
  return __builtin_amdgcn_exp2f(v);
#else
  return exp2f(v);
#endif
}
// inputs PRE-SCALED by log2e (sig) / 2*log2e (tanh gate)
__device__ __forceinline__ float sigp_(float v)  { return rcp_(1.0f + exp2i_(-v)); }
__device__ __forceinline__ float tanhp_(float v) { return 1.0f - 2.0f * rcp_(exp2i_(v) + 1.0f); }
__device__ __forceinline__ float tanhc_(float c) { return 1.0f - 2.0f * rcp_(exp2i_(c * L2E2) + 1.0f); }

__device__ __forceinline__ f16x8 cvt8s(const float* __restrict__ p, float s) {
  float4 a = ((const float4*)p)[0];
  float4 b = ((const float4*)p)[1];
  f16x8 v;
  v[0]=(f16)(a.x*s); v[1]=(f16)(a.y*s); v[2]=(f16)(a.z*s); v[3]=(f16)(a.w*s);
  v[4]=(f16)(b.x*s); v[5]=(f16)(b.y*s); v[6]=(f16)(b.z*s); v[7]=(f16)(b.w*s);
  return v;
}
__device__ __forceinline__ f32x4 mfma16(f16x8 a, f16x8 b, f32x4 c) {
  return __builtin_amdgcn_mfma_f32_16x16x32_f16(a, b, c, 0, 0, 0);
}
__device__ __forceinline__ f32x4 mfma16k16(f16x4 a, f16x4 b, f32x4 c) {
  return __builtin_amdgcn_mfma_f32_16x16x16f16(a, b, c, 0, 0, 0);
}

// v_permlane32_swap: x = {a.lo, b.lo} (even-row spread), y = {a.hi, b.hi} (odd)
__device__ __forceinline__ void pls2_(float a, float b, float& x, float& y) {
#if __has_builtin(__builtin_amdgcn_permlane32_swap)
  i32x2 r = __builtin_amdgcn_permlane32_swap(__float_as_int(a), __float_as_int(b),
                                             false, false);
  x = __int_as_float(r.x); y = __int_as_float(r.y);
#else
  asm volatile("v_permlane32_swap_b32 %0, %1" : "+v"(a), "+v"(b));
  x = a; y = b;
#endif
}

__global__ __launch_bounds__(NTHR)
void lstm_v13(const float* __restrict__ x,
              const float* __restrict__ w_ih0, const float* __restrict__ w_hh0,
              const float* __restrict__ b_ih0, const float* __restrict__ b_hh0,
              const float* __restrict__ w_ih1, const float* __restrict__ w_hh1,
              const float* __restrict__ b_ih1, const float* __restrict__ b_hh1,
              const float* __restrict__ fc_w,  const float* __restrict__ fc_b,
              float* __restrict__ out)
{
  extern __shared__ char lds[];
  char*  w1L   = lds + OFF_W1;
  char*  ringB = lds + OFF_RING;
  char*  hBB   = lds + OFF_HB;
  char*  xT    = lds + OFF_XT;

  const int tid  = (int)threadIdx.x;
  const int lane = tid & 63;
  const int wv   = tid >> 6;          // 0..15
  const int n    = lane & 15;
  const int hi   = lane >> 4;
  const int u0   = (wv & 7) * 16;
  const int blk  = (int)blockIdx.x;
  const int rsw  = (n & 7) << 4;

  // gate scales: q=0(i),1(f),3(o) -> log2e ; q=2(g) -> 2*log2e
  const float SC[4] = { L2E, L2E, L2E2, L2E };

  // ---- stage w_ih1 -> per-wave lane-linear frag banks (pre-scaled) ----
  for (int idx = tid; idx < 8192; idx += NTHR) {
    const int g  = idx >> 4, c  = idx & 15;
    const int w  = (g >> 4) & 7, nn = g & 15, q = g >> 7;
    const int kc = c >> 2,  hh = c & 3;
    f16x8 v = cvt8s(w_ih1 + g*H_ + c*8, SC[q]);
    *(f16x8*)(w1L + w*16384 + (q*4+kc)*1024 + ((hh<<4) + nn)*16) = v;
  }
  // zero ring + hB + xT (16384 B = 4096 dwords); xT zero-fill is load-bearing
  for (int i = tid; i < 4096; i += NTHR) ((unsigned*)ringB)[i] = 0u;

  int offA[4];
  #pragma unroll
  for (int kc = 0; kc < 4; ++kc)
    offA[kc] = (n&7)*256 + ((kc*64 + hi*16) ^ rsw);
  const int rowbase = (hi & 1)*4 + ((lane >= 32) ? 2 : 0);
  const int colb    = 2*(u0 + n);
  const int wOff0 = rowbase*256     + (colb ^ (rowbase<<4));
  const int wOff1 = (rowbase+1)*256 + (colb ^ ((rowbase+1)<<4));
  __syncthreads();

  if (wv < 8) {
    // ================= ROLE 0: layer-0 recurrence (waves 0-7) =================
    float xr0 = 0.f, xr1 = 0.f, xr2 = 0.f;
    if (wv == 7) {
      const int tok = lane >> 3, r = lane & 7;
      const size_t base = (size_t)(blk*R_ + r) * T_;
      f16x4 v; v[0] = (f16)x[(base + tok)*3+0];
               v[1] = (f16)x[(base + tok)*3+1];
               v[2] = (f16)x[(base + tok)*3+2];
               v[3] = (f16)1.f;
      *(f16x4*)(xT + tok*256 + r*32) = v;
      xr0 = x[(base + 8 + tok)*3+0];
      xr1 = x[(base + 8 + tok)*3+1];
      xr2 = x[(base + 8 + tok)*3+2];
    }
    f16x8 whh0f[4][4];
    #pragma unroll
    for (int q = 0; q < 4; ++q)
      #pragma unroll
      for (int kc = 0; kc < 4; ++kc)
        whh0f[q][kc] = cvt8s(w_hh0 + (q*H_ + u0 + n)*H_ + kc*32 + hi*8, SC[q]);
    // K=16 x-proj B-frags: k=0..2 = scaled w_ih0 row, k=3 = scaled fused bias
    f16x4 w0px[4];
    #pragma unroll
    for (int q = 0; q < 4; ++q) {
      const int g = q*H_ + u0 + n;
      f16x4 z; z[0]=(f16)0.f; z[1]=(f16)0.f; z[2]=(f16)0.f; z[3]=(f16)0.f;
      if (hi == 0) {
        z[0] = (f16)(w_ih0[g*3+0]*SC[q]);
        z[1] = (f16)(w_ih0[g*3+1]*SC[q]);
        z[2] = (f16)(w_ih0[g*3+2]*SC[q]);
        z[3] = (f16)((b_ih0[g] + b_hh0[g])*SC[q]);
      }
      w0px[q] = z;
    }
    float cA0 = 0.f, cA1 = 0.f;
    __syncthreads();

    for (int s = 0; s < T_ + 2; ++s) {
      if (wv == 7 && (s & 7) == 3) {
        const int c = s >> 3;
        const int tok = lane >> 3, r = lane & 7;
        if (c <= 61) {
          const size_t base = (size_t)(blk*R_ + r) * T_ + (8*(c+2) + tok);
          const float a0 = x[base*3+0], a1 = x[base*3+1], a2 = x[base*3+2];
          f16x4 v; v[0]=(f16)xr0; v[1]=(f16)xr1; v[2]=(f16)xr2; v[3]=(f16)1.f;
          *(f16x4*)(xT + ((c+1)&1)*2048 + tok*256 + r*32) = v;
          xr0 = a0; xr1 = a1; xr2 = a2;
        } else if (c == 62) {
          f16x4 v; v[0]=(f16)xr0; v[1]=(f16)xr1; v[2]=(f16)xr2; v[3]=(f16)1.f;
          *(f16x4*)(xT + ((c+1)&1)*2048 + tok*256 + r*32) = v;
        }
      }
      if (s < T_) {
        const f16x4 ax = *(const f16x4*)(xT + ((s>>3)&1)*2048 + (s&7)*256
                                         + (n&7)*32 + hi*8);
        const char* pa = ringB + (((s-1)&3)*2048);
        f16x8 af[4];
        #pragma unroll
        for (int kc = 0; kc < 4; ++kc) af[kc] = *(const f16x8*)(pa + offA[kc]);
        f32x4 z4; z4[0]=0.f; z4[1]=0.f; z4[2]=0.f; z4[3]=0.f;
        // gate pair (i,f): MFMA chain then activations overlap pair (g,o)
        f32x4 a0 = mfma16k16(ax, w0px[0], z4);
        f32x4 a1 = mfma16k16(ax, w0px[1], z4);
        #pragma unroll
        for (int kc = 0; kc < 4; ++kc) {
          a0 = mfma16(af[kc], whh0f[0][kc], a0);
          a1 = mfma16(af[kc], whh0f[1][kc], a1);
        }
        float i0, i1, f0, f1, d;
        pls2_(a0[0], a0[2], i0, d); pls2_(a0[1], a0[3], i1, d);
        pls2_(a1[0], a1[2], f0, d); pls2_(a1[1], a1[3], f1, d);
        const float iv0 = sigp_(i0), iv1 = sigp_(i1);
        const float fv0 = sigp_(f0), fv1 = sigp_(f1);
        // gate pair (g,o)
        f32x4 a2 = mfma16k16(ax, w0px[2], z4);
        f32x4 a3 = mfma16k16(ax, w0px[3], z4);
        #pragma unroll
        for (int kc = 0; kc < 4; ++kc) {
          a2 = mfma16(af[kc], whh0f[2][kc], a2);
          a3 = mfma16(af[kc], whh0f[3][kc], a3);
        }
        float g0, g1, o0, o1;
        pls2_(a2[0], a2[2], g0, d); pls2_(a2[1], a2[3], g1, d);
        pls2_(a3[0], a3[2], o0, d); pls2_(a3[1], a3[3], o1, d);
        const float gv0 = tanhp_(g0), gv1 = tanhp_(g1);
        const float ov0 = sigp_(o0),  ov1 = sigp_(o1);
        char* wr = ringB + ((s&3)*2048);
        cA0 = fv0*cA0 + iv0*gv0;
        *(f16*)(wr + wOff0) = (f16)(ov0 * tanhc_(cA0));
        cA1 = fv1*cA1 + iv1*gv1;
        *(f16*)(wr + wOff1) = (f16)(ov1 * tanhc_(cA1));
      }
      __syncthreads();
    }
  } else {
    // ============ ROLE 1: layer-1 recurrence + input proj (waves 8-15) ============
    f16x8 whh1f[4][4];
    #pragma unroll
    for (int q = 0; q < 4; ++q)
      #pragma unroll
      for (int kc = 0; kc < 4; ++kc)
        whh1f[q][kc] = cvt8s(w_hh1 + (q*H_ + u0 + n)*H_ + kc*32 + hi*8, SC[q]);
    float bP[4];
    #pragma unroll
    for (int q = 0; q < 4; ++q) {
      const int g = q*H_ + u0 + n;
      bP[q] = (b_ih1[g] + b_hh1[g]) * SC[q];
    }
    float cB0 = 0.f, cB1 = 0.f;
    f32x4 xpP[4];
    const char* __restrict__ w1lane = w1L + (wv & 7)*16384 + lane*16;
    __syncthreads();

    for (int s = 0; s < T_ + 2; ++s) {
      // proj: tokens (s-2 -> rows 0-7, s-1 -> rows 8-15), even steps
      if ((s & 1) == 0 && s >= 2 && s <= T_) {
        const char* pa = ringB + ((n < 8) ? (((s-2)&3)*2048) : (((s-1)&3)*2048));
        #pragma unroll
        for (int q = 0; q < 4; ++q)
          { xpP[q][0]=bP[q]; xpP[q][1]=bP[q]; xpP[q][2]=bP[q]; xpP[q][3]=bP[q]; }
        #pragma unroll
        for (int kc = 0; kc < 4; ++kc) {
          const f16x8 a = *(const f16x8*)(pa + offA[kc]);
          #pragma unroll
          for (int q = 0; q < 4; ++q) {
            const f16x8 bf = *(const f16x8*)(w1lane + (q*4 + kc)*1024);
            xpP[q] = mfma16(a, bf, xpP[q]);
          }
        }
      }
      // layer 1 (token s-2); odd tokens ride y-half of swap
      if (s >= 2) {
        const bool odd = (s & 1);
        const char* pb = hBB + (s&1)*2048;
        f16x8 af[4];
        #pragma unroll
        for (int kc = 0; kc < 4; ++kc) af[kc] = *(const f16x8*)(pb + offA[kc]);
        // gate pair (i,f)
        f32x4 a0 = xpP[0], a1 = xpP[1];
        #pragma unroll
        for (int kc = 0; kc < 4; ++kc) {
          a0 = mfma16(af[kc], whh1f[0][kc], a0);
          a1 = mfma16(af[kc], whh1f[1][kc], a1);
        }
        float i0, i1, f0, f1, ex, ey;
        pls2_(a0[0], a0[2], ex, ey); i0 = odd ? ey : ex;
        pls2_(a0[1], a0[3], ex, ey); i1 = odd ? ey : ex;
        pls2_(a1[0], a1[2], ex, ey); f0 = odd ? ey : ex;
        pls2_(a1[1], a1[3], ex, ey); f1 = odd ? ey : ex;
        const float iv0 = sigp_(i0), iv1 = sigp_(i1);
        const float fv0 = sigp_(f0), fv1 = sigp_(f1);
        // gate pair (g,o)
        f32x4 a2 = xpP[2], a3 = xpP[3];
        #pragma unroll
        for (int kc = 0; kc < 4; ++kc) {
          a2 = mfma16(af[kc], whh1f[2][kc], a2);
          a3 = mfma16(af[kc], whh1f[3][kc], a3);
        }
        float g0, g1, o0, o1;
        pls2_(a2[0], a2[2], ex, ey); g0 = odd ? ey : ex;
        pls2_(a2[1], a2[3], ex, ey); g1 = odd ? ey : ex;
        pls2_(a3[0], a3[2], ex, ey); o0 = odd ? ey : ex;
        pls2_(a3[1], a3[3], ex, ey); o1 = odd ? ey : ex;
        const float gv0 = tanhp_(g0), gv1 = tanhp_(g1);
        const float ov0 = sigp_(o0),  ov1 = sigp_(o1);
        char* wr = hBB + (((s+1)&1)*2048);
        cB0 = fv0*cB0 + iv0*gv0;
        *(f16*)(wr + wOff0) = (f16)(ov0 * tanhc_(cB0));
        cB1 = fv1*cB1 + iv1*gv1;
        *(f16*)(wr + wOff1) = (f16)(ov1 * tanhc_(cB1));
      }
      __syncthreads();
    }
  }

  // ---- FC head: final h2 in hBB buf (T_+2)&1 == 0 ----
  if (tid < R_*2) {
    const int r = tid >> 1, o = tid & 1;
    float acc = fc_b[o];
    #pragma unroll 4
    for (int d = 0; d < H_; ++d) {
      const f16 hv = *(const f16*)(hBB + r*256 + ((2*d) ^ ((r&7)<<4)));
      acc += (float)hv * fc_w[o*H_ + d];
    }
    out[(blk*R_ + r)*2 + o] = acc;
  }
}

extern "C" void kernel_launch(void* const* d_in, const int* in_sizes, int n_in,
                              void* d_out, int out_size, void* d_ws, size_t ws_size,
                              hipStream_t stream) {
  const float* x     = (const float*)d_in[0];
  const float* w_ih0 = (const float*)d_in[1];
  const float* w_hh0 = (const float*)d_in[2];
  const float* b_ih0 = (const float*)d_in[3];
  const float* b_hh0 = (const float*)d_in[4];
  const float* w_ih1 = (const float*)d_in[5];
  const float* w_hh1 = (const float*)d_in[6];
  const float* b_ih1 = (const float*)d_in[7];
  const float* b_hh1 = (const float*)d_in[8];
  const float* fc_w  = (const float*)d_in[9];
  const float* fc_b  = (const float*)d_in[10];
  (void)in_sizes; (void)n_in; (void)out_size; (void)d_ws; (void)ws_size;

  hipFuncSetAttribute((const void*)lstm_v13,
                      hipFuncAttributeMaxDynamicSharedMemorySize, LDS_BYTES);

  lstm_v13<<<B_/R_, NTHR, LDS_BYTES, stream>>>(
      x, w_ih0, w_hh0, b_ih0, b_hh0, w_ih1, w_hh1, b_ih1, b_hh1,
      fc_w, fc_b, (float*)d_out);
}